// Round 1
// baseline (1308.667 us; speedup 1.0000x reference)
//
#include <hip/hip_runtime.h>
#include <stdint.h>
#include <stddef.h>

// RNN_arch_2_final: 3-cell stacked RNN, T=16, B=16384, hidden 256.
// Strategy: per-WG 64-row batch tile, all T steps in-kernel, h state in LDS
// (bf16, XOR-swizzled), weights pre-packed to MFMA B-frag order in d_ws (bf16).

#define BN 16384
#define TT 16

typedef short s16x8 __attribute__((ext_vector_type(8)));
typedef short s16x4 __attribute__((ext_vector_type(4)));
typedef float f32x4 __attribute__((ext_vector_type(4)));

#define MFMA(a, b, c) __builtin_amdgcn_mfma_f32_16x16x32_bf16((a), (b), (c), 0, 0, 0)

__device__ __forceinline__ short f2bf(float f) {
  union { float f; uint32_t u; } v; v.f = f;
  uint32_t u = v.u;
  u += 0x7FFFu + ((u >> 16) & 1u);   // RNE
  return (short)(u >> 16);
}
__device__ __forceinline__ float bf2f(short s) {
  union { uint32_t u; float f; } v; v.u = ((uint32_t)(uint16_t)s) << 16;
  return v.f;
}
__device__ __forceinline__ float fast_tanh(float xx) {
  float x = fminf(10.f, fmaxf(-10.f, xx));   // clamp: avoid exp overflow -> NaN
  float e = __expf(2.f * x);
  return (e - 1.f) / (e + 1.f);
}
__device__ __forceinline__ void st8f(float* dst, s16x8 s) {
  *(float4*)dst       = make_float4(bf2f(s[0]), bf2f(s[1]), bf2f(s[2]), bf2f(s[3]));
  *(float4*)(dst + 4) = make_float4(bf2f(s[4]), bf2f(s[5]), bf2f(s[6]), bf2f(s[7]));
}

struct PrepPtrs {
  const float *w1i, *w1h, *w1o, *w2i, *w2h, *w2o, *w3i, *w3h, *w3o;
  const float *b1i, *b1h, *b2i, *b2h, *b3i, *b3h, *bo1, *bo2, *bo3, *wfc, *bfc;
};

// Pack weights as bf16 MFMA B-fragments: frag(kt,nt): elem(lane,e) = W[nt*16+(lane&15)][kt*32+(lane>>4)*8+e]
// stored contiguously ((kt*NT+nt)*64+lane)*8. Matrices (N,K,ld,c0):
//  0 W1i(256,64,64,0)  1 W1h(256,256,256,0)  2 W1o(64,256,256,0)
//  3 W2i(256,64,64,0)  4 W2h(256,256,256,0)  5 W2o(64,256,256,0)
//  6 W3ab(256,128,130,2)  7 W3h(256,256,256,0)  8 W3o(64,256,256,0)
__global__ void prep_kernel(PrepPtrs pp, short* __restrict__ wpk, float* __restrict__ wmisc) {
  const float* P[9] = {pp.w1i, pp.w1h, pp.w1o, pp.w2i, pp.w2h, pp.w2o, pp.w3i, pp.w3h, pp.w3o};
  const int LD_[9] = {64, 256, 256, 64, 256, 256, 130, 256, 256};
  const int C0_[9] = {0, 0, 0, 0, 0, 0, 2, 0, 0};
  const int NT_[9] = {16, 16, 4, 16, 16, 4, 16, 16, 4};
  const int DO_[10] = {0, 16384, 81920, 98304, 114688, 180224, 196608, 229376, 294912, 311296};
  int stride = gridDim.x * blockDim.x;
  for (int g = blockIdx.x * blockDim.x + threadIdx.x; g < 311296; g += stride) {
    int m = 0;
    while (g >= DO_[m + 1]) ++m;
    int p = g - DO_[m];
    int NT = NT_[m];
    int frag = p >> 9, lane = (p >> 3) & 63, e = p & 7;
    int kt = frag / NT, nt = frag - kt * NT;
    int row = nt * 16 + (lane & 15);
    int col = kt * 32 + ((lane >> 4) << 3) + e;
    wpk[g] = f2bf(P[m][(size_t)row * LD_[m] + C0_[m] + col]);
  }
  // misc f32 block: bh1(256) bh2(256) bh3(256) bo1(64) bo2(64) bof(64) wfc(128) bfc(2) w3c0(256) w3c1(256)
  for (int i = blockIdx.x * blockDim.x + threadIdx.x; i < 1602; i += stride) {
    float v;
    if      (i < 256)  v = pp.b1i[i]         + pp.b1h[i];
    else if (i < 512)  v = pp.b2i[i - 256]   + pp.b2h[i - 256];
    else if (i < 768)  v = pp.b3i[i - 512]   + pp.b3h[i - 512];
    else if (i < 832)  v = pp.bo1[i - 768];
    else if (i < 896)  v = pp.bo2[i - 832];
    else if (i < 960)  v = pp.bo3[i - 896];
    else if (i < 1088) v = pp.wfc[i - 960];
    else if (i < 1090) v = pp.bfc[i - 1088];
    else if (i < 1346) v = pp.w3i[(size_t)(i - 1090) * 130];
    else               v = pp.w3i[(size_t)(i - 1346) * 130 + 1];
    wmisc[i] = v;
  }
}

__launch_bounds__(512, 2)
__global__ void rnn_main(const float* __restrict__ x, const float* __restrict__ cue,
                         const float* __restrict__ hc1, const float* __restrict__ hc2,
                         const float* __restrict__ hc3, const float* __restrict__ hc4,
                         const short* __restrict__ wpk, const float* __restrict__ wmisc,
                         float* __restrict__ out) {
  // LDS: element (r,c) of h tiles lives at [r*LD + (c ^ ((r&7)<<3))]  (G4 XOR swizzle)
  __shared__ __align__(16) short h1s[64 * 256];
  __shared__ __align__(16) short h2s[64 * 256];
  __shared__ __align__(16) short h3s[64 * 256];
  __shared__ __align__(16) short o12s[64 * 128];   // o1 = cols 0..63, o2 = cols 64..127
  __shared__ __align__(16) float ofl[64 * 68];     // padded f32
  __shared__ float cue0[64], cue1[64];
  __shared__ float misc[1602];

  const int tid = threadIdx.x;
  const int wv = tid >> 6;
  const int lane = tid & 63;
  const int lr = lane & 15;
  const int lq = lane >> 4;
  const int r0 = blockIdx.x * 64;

  float* out_ys  = out;
  float* out_h1  = out + 524288;
  float* out_h2  = out + 4718592;
  float* out_h3  = out + 8912896;
  float* out_h4  = out + 13107200;
  float* out_o1s = out + 17301504;
  float* out_o2s = out + 34078720;
  float* out_cue = out + 50855936;
  float* out_f1  = out + 51380224;
  float* out_f2  = out + 118489088;
  float* out_of  = out + 185597952;

  for (int i = tid; i < 1602; i += 512) misc[i] = wmisc[i];
  if (tid < 64) {
    float cv = cue[r0 + tid];
    cue0[tid] = cv * 10.f;
    cue1[tid] = 10.f * fabsf(cv - 1.f);
  }
  // stage initial h (f32 -> bf16, swizzled) + hc4 passthrough
  for (int i = tid; i < 4096; i += 512) {
    int r = i >> 6, c0 = (i & 63) << 2;
    int li = r * 256 + (c0 ^ ((r & 7) << 3));
    size_t g = (size_t)(r0 + r) * 256 + c0;
    float4 v1 = *(const float4*)(hc1 + g);
    float4 v2 = *(const float4*)(hc2 + g);
    float4 v3 = *(const float4*)(hc3 + g);
    float4 v4 = *(const float4*)(hc4 + g);
    *(s16x4*)&h1s[li] = (s16x4){f2bf(v1.x), f2bf(v1.y), f2bf(v1.z), f2bf(v1.w)};
    *(s16x4*)&h2s[li] = (s16x4){f2bf(v2.x), f2bf(v2.y), f2bf(v2.z), f2bf(v2.w)};
    *(s16x4*)&h3s[li] = (s16x4){f2bf(v3.x), f2bf(v3.y), f2bf(v3.z), f2bf(v3.w)};
    *(float4*)(out_h4 + g) = v4;
  }
  __syncthreads();

  const short* Wp1i  = wpk;
  const short* Wp1h  = wpk + 16384;
  const short* Wp1o  = wpk + 81920;
  const short* Wp2i  = wpk + 98304;
  const short* Wp2h  = wpk + 114688;
  const short* Wp2o  = wpk + 180224;
  const short* Wp3ab = wpk + 196608;
  const short* Wp3h  = wpk + 229376;
  const short* Wp3o  = wpk + 294912;
  const float* bh1v = misc;
  const float* bh2v = misc + 256;
  const float* bh3v = misc + 512;
  const float* bo1v = misc + 768;
  const float* bo2v = misc + 832;
  const float* bofv = misc + 896;
  const float* wfcv = misc + 960;
  const float* bfcv = misc + 1088;
  const float* w3c0 = misc + 1090;
  const float* w3c1 = misc + 1346;

  for (int t = 0; t < TT; ++t) {
    // ---------- Phase A: h1new, h2new (all 8 waves; wave owns cols [32w,32w+32))
    f32x4 acc1[4][2], acc2[4][2];
    #pragma unroll
    for (int j = 0; j < 2; ++j) {
      int n = (2 * wv + j) * 16 + lr;
      float b1 = bh1v[n], b2 = bh2v[n];
      #pragma unroll
      for (int mt = 0; mt < 4; ++mt) {
        acc1[mt][j] = (f32x4){b1, b1, b1, b1};
        acc2[mt][j] = (f32x4){b2, b2, b2, b2};
      }
    }
    #pragma unroll
    for (int kt = 0; kt < 2; ++kt) {  // x part, K=64
      s16x8 af[4];
      #pragma unroll
      for (int mt = 0; mt < 4; ++mt) {
        const float* px = x + ((size_t)t * BN + r0 + mt * 16 + lr) * 64 + kt * 32 + lq * 8;
        float4 a0 = *(const float4*)px;
        float4 a1 = *(const float4*)(px + 4);
        af[mt] = (s16x8){f2bf(a0.x), f2bf(a0.y), f2bf(a0.z), f2bf(a0.w),
                         f2bf(a1.x), f2bf(a1.y), f2bf(a1.z), f2bf(a1.w)};
      }
      #pragma unroll
      for (int j = 0; j < 2; ++j) {
        int nt = 2 * wv + j;
        s16x8 bw1 = *(const s16x8*)(Wp1i + ((size_t)(kt * 16 + nt) * 64 + lane) * 8);
        s16x8 bw2 = *(const s16x8*)(Wp2i + ((size_t)(kt * 16 + nt) * 64 + lane) * 8);
        #pragma unroll
        for (int mt = 0; mt < 4; ++mt) {
          acc1[mt][j] = MFMA(af[mt], bw1, acc1[mt][j]);
          acc2[mt][j] = MFMA(af[mt], bw2, acc2[mt][j]);
        }
      }
    }
    #pragma unroll
    for (int kt = 0; kt < 8; ++kt) {  // recurrent part, K=256
      s16x8 a1f[4], a2f[4];
      #pragma unroll
      for (int mt = 0; mt < 4; ++mt) {
        int r = mt * 16 + lr;
        int c = (kt * 32 + lq * 8) ^ ((r & 7) << 3);
        a1f[mt] = *(const s16x8*)&h1s[r * 256 + c];
        a2f[mt] = *(const s16x8*)&h2s[r * 256 + c];
      }
      #pragma unroll
      for (int j = 0; j < 2; ++j) {
        int nt = 2 * wv + j;
        s16x8 bw1 = *(const s16x8*)(Wp1h + ((size_t)(kt * 16 + nt) * 64 + lane) * 8);
        s16x8 bw2 = *(const s16x8*)(Wp2h + ((size_t)(kt * 16 + nt) * 64 + lane) * 8);
        #pragma unroll
        for (int mt = 0; mt < 4; ++mt) {
          acc1[mt][j] = MFMA(a1f[mt], bw1, acc1[mt][j]);
          acc2[mt][j] = MFMA(a2f[mt], bw2, acc2[mt][j]);
        }
      }
    }
    __syncthreads();  // everyone done reading old h1/h2
    #pragma unroll
    for (int j = 0; j < 2; ++j) {
      int n = (2 * wv + j) * 16 + lr;
      #pragma unroll
      for (int mt = 0; mt < 4; ++mt) {
        #pragma unroll
        for (int q = 0; q < 4; ++q) {
          int r = mt * 16 + lq * 4 + q;
          int c = n ^ ((r & 7) << 3);
          h1s[r * 256 + c] = f2bf(fast_tanh(acc1[mt][j][q]));
          h2s[r * 256 + c] = f2bf(fast_tanh(acc2[mt][j][q]));
        }
      }
    }
    __syncthreads();

    // ---------- Phase B: o1 (waves 0-3) / o2 (waves 4-7)
    {
      const short* hs = (wv < 4) ? h1s : h2s;
      const short* Wo = (wv < 4) ? Wp1o : Wp2o;
      const float* bo = (wv < 4) ? bo1v : bo2v;
      int w4 = wv & 3;
      int n = w4 * 16 + lr;
      float bb = bo[n];
      f32x4 acc[4];
      #pragma unroll
      for (int mt = 0; mt < 4; ++mt) acc[mt] = (f32x4){bb, bb, bb, bb};
      #pragma unroll
      for (int kt = 0; kt < 8; ++kt) {
        s16x8 bw = *(const s16x8*)(Wo + ((size_t)(kt * 4 + w4) * 64 + lane) * 8);
        #pragma unroll
        for (int mt = 0; mt < 4; ++mt) {
          int r = mt * 16 + lr;
          int c = (kt * 32 + lq * 8) ^ ((r & 7) << 3);
          s16x8 af = *(const s16x8*)&hs[r * 256 + c];
          acc[mt] = MFMA(af, bw, acc[mt]);
        }
      }
      int cb = ((wv < 4) ? 0 : 64) + w4 * 16 + lr;
      #pragma unroll
      for (int mt = 0; mt < 4; ++mt) {
        #pragma unroll
        for (int q = 0; q < 4; ++q) {
          int r = mt * 16 + lq * 4 + q;
          o12s[r * 128 + (cb ^ ((r & 7) << 3))] = f2bf(fast_tanh(acc[mt][q]));
        }
      }
    }
    __syncthreads();

    // ---------- Phase C: h3new (all 8 waves)
    {
      f32x4 acc3[4][2];
      #pragma unroll
      for (int j = 0; j < 2; ++j) {
        int n = (2 * wv + j) * 16 + lr;
        float bb = bh3v[n], c0w = w3c0[n], c1w = w3c1[n];
        #pragma unroll
        for (int mt = 0; mt < 4; ++mt) {
          #pragma unroll
          for (int q = 0; q < 4; ++q) {
            int r = mt * 16 + lq * 4 + q;
            acc3[mt][j][q] = bb + cue0[r] * c0w + cue1[r] * c1w;
          }
        }
      }
      #pragma unroll
      for (int kt = 0; kt < 4; ++kt) {  // [o1|o2] part, K=128
        s16x8 af[4];
        #pragma unroll
        for (int mt = 0; mt < 4; ++mt) {
          int r = mt * 16 + lr;
          int c = (kt * 32 + lq * 8) ^ ((r & 7) << 3);
          af[mt] = *(const s16x8*)&o12s[r * 128 + c];
        }
        #pragma unroll
        for (int j = 0; j < 2; ++j) {
          int nt = 2 * wv + j;
          s16x8 bw = *(const s16x8*)(Wp3ab + ((size_t)(kt * 16 + nt) * 64 + lane) * 8);
          #pragma unroll
          for (int mt = 0; mt < 4; ++mt) acc3[mt][j] = MFMA(af[mt], bw, acc3[mt][j]);
        }
      }
      #pragma unroll
      for (int kt = 0; kt < 8; ++kt) {  // recurrent part, K=256
        s16x8 af[4];
        #pragma unroll
        for (int mt = 0; mt < 4; ++mt) {
          int r = mt * 16 + lr;
          int c = (kt * 32 + lq * 8) ^ ((r & 7) << 3);
          af[mt] = *(const s16x8*)&h3s[r * 256 + c];
        }
        #pragma unroll
        for (int j = 0; j < 2; ++j) {
          int nt = 2 * wv + j;
          s16x8 bw = *(const s16x8*)(Wp3h + ((size_t)(kt * 16 + nt) * 64 + lane) * 8);
          #pragma unroll
          for (int mt = 0; mt < 4; ++mt) acc3[mt][j] = MFMA(af[mt], bw, acc3[mt][j]);
        }
      }
      __syncthreads();
      #pragma unroll
      for (int j = 0; j < 2; ++j) {
        int n = (2 * wv + j) * 16 + lr;
        #pragma unroll
        for (int mt = 0; mt < 4; ++mt) {
          #pragma unroll
          for (int q = 0; q < 4; ++q) {
            int r = mt * 16 + lq * 4 + q;
            h3s[r * 256 + (n ^ ((r & 7) << 3))] = f2bf(fast_tanh(acc3[mt][j][q]));
          }
        }
      }
      __syncthreads();
    }

    // ---------- Phase D: of = relu(h3 @ W3o^T + b) (waves 0-3)
    if (wv < 4) {
      int n = wv * 16 + lr;
      float bb = bofv[n];
      f32x4 acc[4];
      #pragma unroll
      for (int mt = 0; mt < 4; ++mt) acc[mt] = (f32x4){bb, bb, bb, bb};
      #pragma unroll
      for (int kt = 0; kt < 8; ++kt) {
        s16x8 bw = *(const s16x8*)(Wp3o + ((size_t)(kt * 4 + wv) * 64 + lane) * 8);
        #pragma unroll
        for (int mt = 0; mt < 4; ++mt) {
          int r = mt * 16 + lr;
          int c = (kt * 32 + lq * 8) ^ ((r & 7) << 3);
          s16x8 af = *(const s16x8*)&h3s[r * 256 + c];
          acc[mt] = MFMA(af, bw, acc[mt]);
        }
      }
      #pragma unroll
      for (int mt = 0; mt < 4; ++mt) {
        #pragma unroll
        for (int q = 0; q < 4; ++q) {
          int r = mt * 16 + lq * 4 + q;
          ofl[r * 68 + n] = fmaxf(0.f, acc[mt][q]);
        }
      }
    }
    __syncthreads();

    // ---------- Phase E: copy-outs + y + cue_arr + feed zero-fill
    {
      size_t ob = ((size_t)t * BN + r0) * 64;
      int r = tid >> 3, c0 = (tid & 7) << 3;
      float4 u0 = *(const float4*)&ofl[r * 68 + c0];
      float4 u1 = *(const float4*)&ofl[r * 68 + c0 + 4];
      *(float4*)(out_of + ob + r * 64 + c0) = u0;
      *(float4*)(out_of + ob + r * 64 + c0 + 4) = u1;
      int sw = (r & 7) << 3;
      s16x8 s1 = *(const s16x8*)&o12s[r * 128 + (c0 ^ sw)];
      s16x8 s2 = *(const s16x8*)&o12s[r * 128 + ((c0 + 64) ^ sw)];
      st8f(out_o1s + ob + r * 64 + c0, s1);
      st8f(out_o2s + ob + r * 64 + c0, s2);
      if (tid < 128) {
        int rr = tid >> 1, jj = tid & 1;
        float s = bfcv[jj];
        const float* wr = wfcv + jj * 64;
        #pragma unroll 8
        for (int k = 0; k < 64; ++k) s += ofl[rr * 68 + k] * wr[k];
        size_t yi = ((size_t)t * BN + r0 + rr) * 2 + jj;
        out_ys[yi] = s;
        out_cue[yi] = jj ? cue1[rr] : cue0[rr];
      }
      size_t fb = ((size_t)t * BN + r0) * 256;
      float4 z = make_float4(0.f, 0.f, 0.f, 0.f);
      #pragma unroll
      for (int i = 0; i < 8; ++i) {
        *(float4*)(out_f1 + fb + (size_t)(i * 512 + tid) * 4) = z;
        *(float4*)(out_f2 + fb + (size_t)(i * 512 + tid) * 4) = z;
      }
    }
    // no barrier needed: next writers of o12s/ofl are >=2 barriers away
  }

  // final h states (bf16 LDS -> f32 global)
  for (int i = tid; i < 4096; i += 512) {
    int r = i >> 6, c0 = (i & 63) << 2;
    int li = r * 256 + (c0 ^ ((r & 7) << 3));
    size_t g = (size_t)(r0 + r) * 256 + c0;
    s16x4 s1 = *(const s16x4*)&h1s[li];
    s16x4 s2 = *(const s16x4*)&h2s[li];
    s16x4 s3 = *(const s16x4*)&h3s[li];
    *(float4*)(out_h1 + g) = make_float4(bf2f(s1[0]), bf2f(s1[1]), bf2f(s1[2]), bf2f(s1[3]));
    *(float4*)(out_h2 + g) = make_float4(bf2f(s2[0]), bf2f(s2[1]), bf2f(s2[2]), bf2f(s2[3]));
    *(float4*)(out_h3 + g) = make_float4(bf2f(s3[0]), bf2f(s3[1]), bf2f(s3[2]), bf2f(s3[3]));
  }
}

extern "C" void kernel_launch(void* const* d_in, const int* in_sizes, int n_in,
                              void* d_out, int out_size, void* d_ws, size_t ws_size,
                              hipStream_t stream) {
  const float* x   = (const float*)d_in[0];
  const float* cue = (const float*)d_in[1];
  const float* hc1 = (const float*)d_in[2];
  const float* hc2 = (const float*)d_in[3];
  const float* hc3 = (const float*)d_in[4];
  const float* hc4 = (const float*)d_in[5];
  PrepPtrs pp;
  pp.w1i = (const float*)d_in[6];  pp.b1i = (const float*)d_in[7];
  pp.w1h = (const float*)d_in[8];  pp.b1h = (const float*)d_in[9];
  pp.w1o = (const float*)d_in[10]; pp.bo1 = (const float*)d_in[11];
  pp.w2i = (const float*)d_in[12]; pp.b2i = (const float*)d_in[13];
  pp.w2h = (const float*)d_in[14]; pp.b2h = (const float*)d_in[15];
  pp.w2o = (const float*)d_in[16]; pp.bo2 = (const float*)d_in[17];
  pp.w3i = (const float*)d_in[18]; pp.b3i = (const float*)d_in[19];
  pp.w3h = (const float*)d_in[20]; pp.b3h = (const float*)d_in[21];
  pp.w3o = (const float*)d_in[22]; pp.bo3 = (const float*)d_in[23];
  pp.wfc = (const float*)d_in[24]; pp.bfc = (const float*)d_in[25];

  short* wpk   = (short*)d_ws;                       // 311296 bf16 = 622592 B
  float* wmisc = (float*)((char*)d_ws + 622592);     // 1602 f32

  prep_kernel<<<64, 256, 0, stream>>>(pp, wpk, wmisc);
  rnn_main<<<256, 512, 0, stream>>>(x, cue, hc1, hc2, hc3, hc4, wpk, wmisc, (float*)d_out);
}